// Round 9
// baseline (45.024 us; speedup 1.0000x reference)
//
#include <hip/hip_runtime.h>

// 5x5 lower-median filter, reflect padding, fp32 in/out, x: [8,3,512,512]
// R9: occupancy-first. 4x1 px per thread, 6 packed cols x 5 rows in flight
// (~30 h2 live), __launch_bounds__(256,6) -> target <=85 VGPR, 6 waves/SIMD.
// asm v_pk_min/max_f16 comparators (R6-proven), merge-based rank-7-of-13.
static constexpr int H = 512, W = 512;
static constexpr int QX_I = 126;                     // interior x-tiles (x0=4..504)
static constexpr int TILES_I = QX_I * 508;           // 64008 (y = 2..509)
static constexpr int IB = (TILES_I + 255) / 256;     // 251 interior blocks/img
static constexpr int EDGE_N = 2 * 512 + 4 * QX_I;    // 1528 edge tiles/img
static constexpr int EB = (EDGE_N + 255) / 256;      // 6 edge blocks/img

typedef __fp16 h2 __attribute__((ext_vector_type(2)));
typedef float f4u __attribute__((ext_vector_type(4), aligned(4)));
typedef float f4a __attribute__((ext_vector_type(4), aligned(16)));

// packed single-instruction comparators (non-volatile asm: CSE/schedulable)
__device__ __forceinline__ h2 PMN(h2 a, h2 b) {
    h2 d; asm("v_pk_min_f16 %0, %1, %2" : "=v"(d) : "v"(a), "v"(b)); return d;
}
__device__ __forceinline__ h2 PMX(h2 a, h2 b) {
    h2 d; asm("v_pk_max_f16 %0, %1, %2" : "=v"(d) : "v"(a), "v"(b)); return d;
}
__device__ __forceinline__ void PCE(h2& a, h2& b) {
    h2 lo = PMN(a, b), hi = PMX(a, b); a = lo; b = hi;
}
// med3(t,u,x) given u <= t  ==  max(u, min(t,x))
__device__ __forceinline__ h2 IMD(h2 t, h2 u, h2 x) { return PMX(u, PMN(t, x)); }

// 9-CE optimal sort5 (ascending)
__device__ __forceinline__ void sort5p(h2& a0, h2& a1, h2& a2, h2& a3, h2& a4) {
    PCE(a0,a1); PCE(a3,a4); PCE(a2,a4); PCE(a2,a3); PCE(a0,a3);
    PCE(a0,a2); PCE(a1,a4); PCE(a1,a3); PCE(a1,a2);
}

// Lower median (rank 12 of 25) for pack-window B of column-sorted packs
// S[5][6]: lo half = window at cols B..B+4, hi half = cols B+2..B+6.
// Stage 1: sorted-column row exclusion -> sorted runs A2,B3,C3,D3,E2.
// Stage 2: G=merge(A,E); F=merge(B,C); H=merge(D,G); rank-7-of-13 identity.
template<int B>
__device__ __forceinline__ h2 med25p(const h2 S[5][6]) {
    // rowA (col minima): keep top2, u<=t
    h2 u = PMN(S[0][B], S[0][B+1]), t = PMX(S[0][B], S[0][B+1]);
    u = IMD(t, u, S[0][B+2]); t = PMX(t, S[0][B+2]);
    u = IMD(t, u, S[0][B+3]); t = PMX(t, S[0][B+3]);
    u = IMD(t, u, S[0][B+4]); t = PMX(t, S[0][B+4]);
    h2 A0 = u, A1 = t;
    // rowB: keep top3 sorted l<=m<=h
    h2 mn1 = PMN(S[1][B], S[1][B+1]), mx1 = PMX(S[1][B], S[1][B+1]);
    h2 l = PMN(mn1, S[1][B+2]), h = PMX(mx1, S[1][B+2]);
    h2 m = PMX(mn1, PMN(mx1, S[1][B+2]));
    { h2 x = S[1][B+3]; h2 nl = IMD(m,l,x), nm = IMD(h,m,x), nh = PMX(h,x); l=nl; m=nm; h=nh; }
    { h2 x = S[1][B+4]; h2 nl = IMD(m,l,x), nm = IMD(h,m,x), nh = PMX(h,x); l=nl; m=nm; h=nh; }
    h2 B0 = l, B1 = m, B2 = h;
    // rowC (col medians): keep middle3
    h2 mn2 = PMN(S[2][B], S[2][B+1]), mx2 = PMX(S[2][B], S[2][B+1]);
    h2 l2 = PMN(mn2, S[2][B+2]), hh = PMX(mx2, S[2][B+2]);
    h2 m2 = PMX(mn2, PMN(mx2, S[2][B+2]));
    h2 d4 = S[2][B+3];
    h2 s0 = PMN(l2, d4), s1 = IMD(m2, l2, d4), s2 = IMD(hh, m2, d4), s3 = PMX(hh, d4);
    h2 e4 = S[2][B+4];
    h2 C0 = IMD(s1, s0, e4), C1 = IMD(s2, s1, e4), C2 = IMD(s3, s2, e4);
    // rowD: keep bottom3
    h2 mn3 = PMN(S[3][B], S[3][B+1]), mx3 = PMX(S[3][B], S[3][B+1]);
    h2 l3 = PMN(mn3, S[3][B+2]), h3 = PMX(mx3, S[3][B+2]);
    h2 m3 = PMX(mn3, PMN(mx3, S[3][B+2]));
    { h2 x = S[3][B+3]; h2 nl = PMN(l3,x), nm = IMD(m3,l3,x), nh = IMD(h3,m3,x); l3=nl; m3=nm; h3=nh; }
    { h2 x = S[3][B+4]; h2 nl = PMN(l3,x), nm = IMD(m3,l3,x), nh = IMD(h3,m3,x); l3=nl; m3=nm; h3=nh; }
    h2 D0 = l3, D1 = m3, D2 = h3;
    // rowE (col maxima): keep bottom2, p<=q
    h2 p = PMN(S[4][B], S[4][B+1]), q = PMX(S[4][B], S[4][B+1]);
    q = IMD(q, p, S[4][B+2]); p = PMN(p, S[4][B+2]);
    q = IMD(q, p, S[4][B+3]); p = PMN(p, S[4][B+3]);
    q = IMD(q, p, S[4][B+4]); p = PMN(p, S[4][B+4]);
    h2 E0 = p, E1 = q;

    // G4 = merge(A2, E2): (A0,E0,A1,E1)
    PCE(A0, E0); PCE(A1, E1); PCE(E0, A1);
    h2 G0 = A0, G1 = E0, G2 = A1, G3 = E1;
    // F6 = merge(B3, C3): odd-even merge -> (B0,B1,C0,C1,B2,C2)
    PCE(B0, C0); PCE(B2, C2); PCE(C0, B2);
    PCE(B1, C1);
    PCE(B1, C0); PCE(C1, B2);
    h2 F0 = B0, F1 = B1, F2 = C0, F3 = C1, F4 = B2, F5 = C2;
    // H7 = merge(D3, G4): odd-even merge -> (D0,D1,G0,G1,D2,G3,G2)
    PCE(D0, G0); PCE(D2, G2); PCE(G0, D2);
    PCE(D1, G1); PCE(G1, G3);
    PCE(D1, G0); PCE(G1, D2); PCE(G3, G2);
    h2 H0 = D0, H1 = D1, H2 = G0, H3 = G1, H4 = D2, H5 = G3, H6 = G2;
    // median of 13 = 7th of F(6) U H(7) = min over i+j=7 of max(F[i-1],H[j-1])
    h2 r = PMN(H6, PMX(F0, H5));
    r = PMN(r, PMX(F1, H4));
    r = PMN(r, PMX(F2, H3));
    r = PMN(r, PMX(F3, H2));
    r = PMN(r, PMX(F4, H1));
    r = PMN(r, PMX(F5, H0));
    return r;
}

__device__ __forceinline__ int refl(int z, int n) {
    z = (z < 0) ? -z : z;
    return (z >= n) ? 2 * n - 2 - z : z;
}

__global__ __launch_bounds__(256, 6) void median5x5_kernel(const float* __restrict__ in,
                                                           float* __restrict__ out) {
    int bc = blockIdx.y;
    const float* __restrict__ img = in + (size_t)bc * (H * W);
    float* __restrict__ outc = out + (size_t)bc * (H * W);

    // P[r][k] = packed (col x0-2+k, col x0+k) of row y-2+r; k = 0..5
    h2 P[5][6];
    int x0, y;
    if ((int)blockIdx.x < IB) {
        int i = blockIdx.x * 256 + threadIdx.x;
        if (i >= TILES_I) return;
        int r  = i / QX_I;           // 0..507
        int qx = i - r * QX_I;       // 0..125
        x0 = 4 * (qx + 1);           // 4..504
        y  = r + 2;                  // 2..509
        const float* p = img + (y - 2) * W + (x0 - 2);
        #pragma unroll
        for (int rr = 0; rr < 5; ++rr) {
            f4u a = *(const f4u*)(p + rr * W);       // cols x0-2..x0+1
            f4u b = *(const f4u*)(p + rr * W + 4);   // cols x0+2..x0+5
            P[rr][0] = __builtin_amdgcn_cvt_pkrtz(a.x, a.z);
            P[rr][1] = __builtin_amdgcn_cvt_pkrtz(a.y, a.w);
            P[rr][2] = __builtin_amdgcn_cvt_pkrtz(a.z, b.x);
            P[rr][3] = __builtin_amdgcn_cvt_pkrtz(a.w, b.y);
            P[rr][4] = __builtin_amdgcn_cvt_pkrtz(b.x, b.z);
            P[rr][5] = __builtin_amdgcn_cvt_pkrtz(b.y, b.w);
        }
    } else {
        int j = ((int)blockIdx.x - IB) * 256 + threadIdx.x;
        if (j >= EDGE_N) return;
        int qx;
        if (j < 1024) { qx = (j & 1) ? 127 : 0; y = j >> 1; }
        else {
            int k2  = j - 1024;                 // 0..503
            int sub = k2 / QX_I;                // 0..3
            const int ys[4] = { 0, 1, 510, 511 };
            y  = ys[sub];
            qx = 1 + (k2 - sub * QX_I);         // 1..126
        }
        x0 = 4 * qx;
        int ry[5], rx[8];
        #pragma unroll
        for (int i2 = 0; i2 < 5; ++i2) ry[i2] = refl(y - 2 + i2, H);
        #pragma unroll
        for (int k = 0; k < 8; ++k) rx[k] = refl(x0 - 2 + k, W);
        #pragma unroll
        for (int rr = 0; rr < 5; ++rr) {
            float tmp[8];
            #pragma unroll
            for (int k = 0; k < 8; ++k) tmp[k] = img[ry[rr] * W + rx[k]];
            #pragma unroll
            for (int k = 0; k < 6; ++k)
                P[rr][k] = __builtin_amdgcn_cvt_pkrtz(tmp[k], tmp[k + 2]);
        }
    }

    // sort each packed column of 5 (9-CE network)
    #pragma unroll
    for (int k = 0; k < 6; ++k)
        sort5p(P[0][k], P[1][k], P[2][k], P[3][k], P[4][k]);

    // window B=0 -> outputs (x0, x0+2); B=1 -> (x0+1, x0+3)
    h2 r0 = med25p<0>(P);
    h2 r1 = med25p<1>(P);
    f4a res;
    res.x = (float)r0.x; res.y = (float)r1.x;
    res.z = (float)r0.y; res.w = (float)r1.y;
    *(f4a*)(outc + y * W + x0) = res;
}

extern "C" void kernel_launch(void* const* d_in, const int* in_sizes, int n_in,
                              void* d_out, int out_size, void* d_ws, size_t ws_size,
                              hipStream_t stream) {
    const float* x = (const float*)d_in[0];
    float* out = (float*)d_out;
    int n_bc = in_sizes[0] / (H * W);       // 24
    dim3 grid(IB + EB, n_bc, 1);
    median5x5_kernel<<<grid, 256, 0, stream>>>(x, out);
}

// Round 10
// 32.445 us; speedup vs baseline: 1.3877x; 1.3877x over previous
//
#include <hip/hip_runtime.h>

// 5x5 lower-median filter, reflect padding, fp32 in/out, x: [8,3,512,512]
// R10: LDS-staged. Block = 256x16 output tile; halo (264x20) staged ONCE to
// LDS as packed fp16 (one global read per input element), consumed 5x via
// ds_read_b64 + v_perm repacking. Packed windows: lo = px x0+B, hi = x0+2+B.
static constexpr int H = 512, W = 512;
static constexpr int TX = 64, TY = 4;          // thread grid in block
static constexpr int TILE_W = 256, TILE_H = 16;
static constexpr int SROWS = TILE_H + 4;       // 20 staged rows
static constexpr int SUNITS = 66;              // 66 b64-units (264 halfs) per row
static constexpr int USTRIDE = 67;             // padded unit stride (bank rotate)
static constexpr int NTASK = SROWS * SUNITS;   // 1320 staging tasks

typedef __fp16 h2 __attribute__((ext_vector_type(2)));
typedef float f4u __attribute__((ext_vector_type(4), aligned(4)));
typedef float f4a __attribute__((ext_vector_type(4), aligned(16)));
typedef unsigned int u32;
typedef u32 u32x2 __attribute__((ext_vector_type(2), aligned(8)));

__device__ __forceinline__ h2 PMN(h2 a, h2 b) {
    h2 d; asm("v_pk_min_f16 %0, %1, %2" : "=v"(d) : "v"(a), "v"(b)); return d;
}
__device__ __forceinline__ h2 PMX(h2 a, h2 b) {
    h2 d; asm("v_pk_max_f16 %0, %1, %2" : "=v"(d) : "v"(a), "v"(b)); return d;
}
__device__ __forceinline__ void PCE(h2& a, h2& b) {
    h2 lo = PMN(a, b), hi = PMX(a, b); a = lo; b = hi;
}
__device__ __forceinline__ h2 IMD(h2 t, h2 u, h2 x) { return PMX(u, PMN(t, x)); }

__device__ __forceinline__ void sort5p(h2& a0, h2& a1, h2& a2, h2& a3, h2& a4) {
    PCE(a0,a1); PCE(a3,a4); PCE(a2,a4); PCE(a2,a3); PCE(a0,a3);
    PCE(a0,a2); PCE(a1,a4); PCE(a1,a3); PCE(a1,a2);
}

// Lower median (rank 12 of 25) for pack-window B of column-sorted packs
// S[5][6]: lo half = window cols B..B+4, hi half = cols B+2..B+6.
template<int B>
__device__ __forceinline__ h2 med25p(const h2 S[5][6]) {
    // rowA (col minima): keep top2, u<=t
    h2 u = PMN(S[0][B], S[0][B+1]), t = PMX(S[0][B], S[0][B+1]);
    u = IMD(t, u, S[0][B+2]); t = PMX(t, S[0][B+2]);
    u = IMD(t, u, S[0][B+3]); t = PMX(t, S[0][B+3]);
    u = IMD(t, u, S[0][B+4]); t = PMX(t, S[0][B+4]);
    h2 A0 = u, A1 = t;
    // rowB: keep top3 sorted l<=m<=h
    h2 mn1 = PMN(S[1][B], S[1][B+1]), mx1 = PMX(S[1][B], S[1][B+1]);
    h2 l = PMN(mn1, S[1][B+2]), h = PMX(mx1, S[1][B+2]);
    h2 m = PMX(mn1, PMN(mx1, S[1][B+2]));
    { h2 x = S[1][B+3]; h2 nl = IMD(m,l,x), nm = IMD(h,m,x), nh = PMX(h,x); l=nl; m=nm; h=nh; }
    { h2 x = S[1][B+4]; h2 nl = IMD(m,l,x), nm = IMD(h,m,x), nh = PMX(h,x); l=nl; m=nm; h=nh; }
    h2 B0 = l, B1 = m, B2 = h;
    // rowC (col medians): keep middle3
    h2 mn2 = PMN(S[2][B], S[2][B+1]), mx2 = PMX(S[2][B], S[2][B+1]);
    h2 l2 = PMN(mn2, S[2][B+2]), hh = PMX(mx2, S[2][B+2]);
    h2 m2 = PMX(mn2, PMN(mx2, S[2][B+2]));
    h2 d4 = S[2][B+3];
    h2 s0 = PMN(l2, d4), s1 = IMD(m2, l2, d4), s2 = IMD(hh, m2, d4), s3 = PMX(hh, d4);
    h2 e4 = S[2][B+4];
    h2 C0 = IMD(s1, s0, e4), C1 = IMD(s2, s1, e4), C2 = IMD(s3, s2, e4);
    // rowD: keep bottom3
    h2 mn3 = PMN(S[3][B], S[3][B+1]), mx3 = PMX(S[3][B], S[3][B+1]);
    h2 l3 = PMN(mn3, S[3][B+2]), h3 = PMX(mx3, S[3][B+2]);
    h2 m3 = PMX(mn3, PMN(mx3, S[3][B+2]));
    { h2 x = S[3][B+3]; h2 nl = PMN(l3,x), nm = IMD(m3,l3,x), nh = IMD(h3,m3,x); l3=nl; m3=nm; h3=nh; }
    { h2 x = S[3][B+4]; h2 nl = PMN(l3,x), nm = IMD(m3,l3,x), nh = IMD(h3,m3,x); l3=nl; m3=nm; h3=nh; }
    h2 D0 = l3, D1 = m3, D2 = h3;
    // rowE (col maxima): keep bottom2, p<=q
    h2 p = PMN(S[4][B], S[4][B+1]), q = PMX(S[4][B], S[4][B+1]);
    q = IMD(q, p, S[4][B+2]); p = PMN(p, S[4][B+2]);
    q = IMD(q, p, S[4][B+3]); p = PMN(p, S[4][B+3]);
    q = IMD(q, p, S[4][B+4]); p = PMN(p, S[4][B+4]);
    h2 E0 = p, E1 = q;
    // G4 = merge(A2, E2)
    PCE(A0, E0); PCE(A1, E1); PCE(E0, A1);
    h2 G0 = A0, G1 = E0, G2 = A1, G3 = E1;
    // F6 = merge(B3, C3)
    PCE(B0, C0); PCE(B2, C2); PCE(C0, B2);
    PCE(B1, C1);
    PCE(B1, C0); PCE(C1, B2);
    h2 F0 = B0, F1 = B1, F2 = C0, F3 = C1, F4 = B2, F5 = C2;
    // H7 = merge(D3, G4)
    PCE(D0, G0); PCE(D2, G2); PCE(G0, D2);
    PCE(D1, G1); PCE(G1, G3);
    PCE(D1, G0); PCE(G1, D2); PCE(G3, G2);
    h2 H0 = D0, H1 = D1, H2 = G0, H3 = G1, H4 = D2, H5 = G3, H6 = G2;
    // median of 13 = min over i+j=7 of max(F[i-1], H[j-1])
    h2 r = PMN(H6, PMX(F0, H5));
    r = PMN(r, PMX(F1, H4));
    r = PMN(r, PMX(F2, H3));
    r = PMN(r, PMX(F3, H2));
    r = PMN(r, PMX(F4, H1));
    r = PMN(r, PMX(F5, H0));
    return r;
}

// (wa.lo16, wb.lo16) and (wa.hi16, wb.hi16) as one u32 pack
__device__ __forceinline__ u32 PKLO(u32 wa, u32 wb) {
    return __builtin_amdgcn_perm(wb, wa, 0x05040100u);
}
__device__ __forceinline__ u32 PKHI(u32 wa, u32 wb) {
    return __builtin_amdgcn_perm(wb, wa, 0x07060302u);
}
__device__ __forceinline__ h2 asH2(u32 v) { return __builtin_bit_cast(h2, v); }

__device__ __forceinline__ int refl(int z, int n) {
    z = (z < 0) ? -z : z;
    return (z >= n) ? 2 * n - 2 - z : z;
}

__global__ __launch_bounds__(256, 8) void median5x5_kernel(const float* __restrict__ in,
                                                           float* __restrict__ out) {
    __shared__ u32x2 lds[SROWS * USTRIDE];   // 10720 B

    int bc = blockIdx.y;
    const float* __restrict__ img = in + (size_t)bc * (H * W);
    float* __restrict__ outc = out + (size_t)bc * (H * W);

    int tile_x = blockIdx.x & 1;             // 0,1
    int tile_y = (int)blockIdx.x >> 1;       // 0..31
    int x_base = tile_x * TILE_W;
    int y_base = tile_y * TILE_H;

    // ---- stage halo: rows y_base-2..y_base+17, cols x_base-4..x_base+259 ----
    for (int t = threadIdx.x; t < NTASK; t += 256) {
        int sr = t / SUNITS;
        int u  = t - sr * SUNITS;
        int gy  = refl(y_base - 2 + sr, H);
        int gc0 = x_base - 4 + 4 * u;
        f4u v;
        if (gc0 >= 0 && gc0 <= W - 4) {
            v = *(const f4u*)(img + gy * W + gc0);
        } else {
            const float* rowp = img + gy * W;
            v.x = rowp[refl(gc0,     W)];
            v.y = rowp[refl(gc0 + 1, W)];
            v.z = rowp[refl(gc0 + 2, W)];
            v.w = rowp[refl(gc0 + 3, W)];
        }
        u32x2 pk;
        pk.x = __builtin_bit_cast(u32, __builtin_amdgcn_cvt_pkrtz(v.x, v.y));
        pk.y = __builtin_bit_cast(u32, __builtin_amdgcn_cvt_pkrtz(v.z, v.w));
        lds[sr * USTRIDE + u] = pk;
    }
    __syncthreads();

    // ---- consume: thread (tx,ty) -> 4 px wide at x0, 4 rows at y0 ----
    int tx = threadIdx.x & 63;
    int ty = (int)threadIdx.x >> 6;
    int x0 = x_base + 4 * tx;
    int y0 = y_base + 4 * ty;

    #pragma unroll
    for (int r = 0; r < 4; ++r) {
        h2 S[5][6];
        #pragma unroll
        for (int i = 0; i < 5; ++i) {
            int lr = 4 * ty + r + i;                       // LDS row 0..35? (<=19)
            const u32x2* rowp = &lds[lr * USTRIDE + tx];   // units tx..tx+2
            u32x2 q0 = rowp[0], q1 = rowp[1], q2 = rowp[2];
            u32 w1 = q0.y, w2 = q1.x, w3 = q1.y, w4 = q2.x;
            // P[k] = (col x0-2+k, col x0+k): halfs h[k+2], h[k+4]
            S[i][0] = asH2(PKLO(w1, w2));
            S[i][1] = asH2(PKHI(w1, w2));
            S[i][2] = asH2(PKLO(w2, w3));
            S[i][3] = asH2(PKHI(w2, w3));
            S[i][4] = asH2(PKLO(w3, w4));
            S[i][5] = asH2(PKHI(w3, w4));
        }
        #pragma unroll
        for (int k = 0; k < 6; ++k)
            sort5p(S[0][k], S[1][k], S[2][k], S[3][k], S[4][k]);
        h2 r0 = med25p<0>(S);
        h2 r1 = med25p<1>(S);
        f4a res;
        res.x = (float)r0.x; res.y = (float)r1.x;
        res.z = (float)r0.y; res.w = (float)r1.y;
        *(f4a*)(outc + (y0 + r) * W + x0) = res;
    }
}

extern "C" void kernel_launch(void* const* d_in, const int* in_sizes, int n_in,
                              void* d_out, int out_size, void* d_ws, size_t ws_size,
                              hipStream_t stream) {
    const float* x = (const float*)d_in[0];
    float* out = (float*)d_out;
    int n_bc = in_sizes[0] / (H * W);       // 24
    dim3 grid((W / TILE_W) * (H / TILE_H), n_bc, 1);   // (64, 24)
    median5x5_kernel<<<grid, 256, 0, stream>>>(x, out);
}